// Round 4
// baseline (288.566 us; speedup 1.0000x reference)
//
#include <hip/hip_runtime.h>

#define S_LEN 4096   // H*W
#define C_CH  256
#define D_CH  128
#define NT2   64     // t-tiles of 64
#define PITCH 72     // P staging pitch (elements)
// softmax scale folded into exp2: lambda = (1/sqrt(256)) * log2(e)
#define LAMBDA 0.09016844005555896f

typedef __attribute__((ext_vector_type(8))) short short8;   // 8 x bf16 (4 VGPR)
typedef __attribute__((ext_vector_type(4))) float f32x4;

static __device__ __forceinline__ unsigned short f2bf(float x) {
    union { float f; unsigned u; } v; v.f = x;
    unsigned r = v.u + 0x7FFFu + ((v.u >> 16) & 1u);   // RNE
    return (unsigned short)(r >> 16);
}

static __device__ __forceinline__ void gload_lds16(const void* g, void* l) {
    __builtin_amdgcn_global_load_lds(
        (const __attribute__((address_space(1))) void*)g,
        (__attribute__((address_space(3))) void*)l, 16, 0, 0);
}

// ---------- kernel 1: x f32 -> xb bf16, layout [n][c][s] (V operand) ----------
__global__ void nlm_conv_kernel(const float* __restrict__ x, unsigned short* __restrict__ xb) {
    size_t base = ((size_t)blockIdx.x * 256 + threadIdx.x) * 4;
    float4 v = *reinterpret_cast<const float4*>(x + base);
    ushort4 b; b.x = f2bf(v.x); b.y = f2bf(v.y); b.z = f2bf(v.z); b.w = f2bf(v.w);
    *reinterpret_cast<ushort4*>(xb + base) = b;
}

// ---------- kernel 2: theta_w/phi_w f32 -> bf16, wb = [2][128][256] ----------
__global__ void nlm_wconv_kernel(const float* __restrict__ tw, const float* __restrict__ pw,
                                 unsigned short* __restrict__ wb) {
    int base = (blockIdx.x * 256 + threadIdx.x) * 4;
    const float* src = (base < 32768) ? (tw + base) : (pw + base - 32768);
    float4 v = *reinterpret_cast<const float4*>(src);
    ushort4 b; b.x = f2bf(v.x); b.y = f2bf(v.y); b.z = f2bf(v.z); b.w = f2bf(v.w);
    *reinterpret_cast<ushort4*>(wb + base) = b;
}

// ---------- kernel 3: projections Q[n][s][128], K[n][t][128] (bf16) ----------
__launch_bounds__(256, 1)
__global__ void nlm_proj_kernel(const float* __restrict__ x,
                                const unsigned short* __restrict__ wb,
                                const float* __restrict__ tb, const float* __restrict__ pbias,
                                unsigned short* __restrict__ Qb, unsigned short* __restrict__ Kb) {
    const int n    = blockIdx.y;
    const int wave = threadIdx.x >> 6;
    const int lane = threadIdx.x & 63;
    const int sl   = lane & 15, g = lane >> 4;
    const int s0   = blockIdx.x * 64 + wave * 16;
    const float* xn = x + (size_t)n * C_CH * S_LEN;

    f32x4 acc[16];
    #pragma unroll
    for (int i = 0; i < 16; ++i) acc[i] = (f32x4){0.f, 0.f, 0.f, 0.f};

    #pragma unroll 1
    for (int cc = 0; cc < 8; ++cc) {
        short8 af;                                   // A[m=s][k=c]: lane m=sl, k=g*8+j
        #pragma unroll
        for (int j = 0; j < 8; ++j) {
            float v = xn[(size_t)(cc * 32 + g * 8 + j) * S_LEN + s0 + sl];
            af[j] = (short)f2bf(v);
        }
        #pragma unroll
        for (int t = 0; t < 16; ++t) {               // 0..7 theta tiles, 8..15 phi tiles
            const unsigned short* wp = wb + (size_t)(t >> 3) * (D_CH * C_CH)
                                          + (size_t)((t & 7) * 16 + sl) * C_CH + cc * 32 + g * 8;
            short8 bf = *reinterpret_cast<const short8*>(wp);
            acc[t] = __builtin_amdgcn_mfma_f32_16x16x32_bf16(af, bf, acc[t], 0, 0, 0);
        }
    }
    unsigned short* Qn = Qb + (size_t)n * S_LEN * D_CH;
    unsigned short* Kn = Kb + (size_t)n * S_LEN * D_CH;
    #pragma unroll
    for (int t = 0; t < 16; ++t) {
        const float bias = (t < 8 ? tb : pbias)[(t & 7) * 16 + sl];
        unsigned short* dst = (t < 8 ? Qn : Kn);
        #pragma unroll
        for (int r = 0; r < 4; ++r) {                // D row = g*4+r, col = sl
            dst[(size_t)(s0 + g * 4 + r) * D_CH + (t & 7) * 16 + sl] = f2bf(acc[t][r] + bias);
        }
    }
}

// ---------- kernel 4: flash attention, O^T = V^T * P^T ----------
// 512 blocks (2/CU), 4 waves, 32 q-rows/block. Wave w: s-group (w&1), i-half (w>>1).
// BT=64. K: 3-deep LDS pipeline (global_load_lds, XOR-swizzled), ONE barrier/iter,
// counted vmcnt. V: direct global->VGPR, register double-buffered 1 iter ahead.
__launch_bounds__(256, 2)
__global__ void nlm_attn_kernel(const unsigned short* __restrict__ Qb,
                                const unsigned short* __restrict__ Kb,
                                const unsigned short* __restrict__ xb,
                                float* __restrict__ out) {
    // XCD swizzle: 512 blocks, 64 consecutive work-items per XCD; 2 XCDs per batch n.
    const int sid  = blockIdx.x;
    const int newb = (sid & 7) * 64 + (sid >> 3);
    const int n    = newb >> 7;
    const int bx   = newb & 127;
    const int wave = threadIdx.x >> 6;
    const int lane = threadIdx.x & 63;
    const int sl   = lane & 15, g = lane >> 4;
    const int s0   = bx * 32 + (wave & 1) * 16;
    const int ih   = wave >> 1;                      // i-half: channels ih*128..ih*128+127

    __shared__ unsigned short Klds[3][64 * 128];     // [t-local][d], chunk-XOR swizzled
    __shared__ unsigned short Plds[4][16 * PITCH];   // per-wave P^T staging

    const unsigned short* Qn = Qb + (size_t)n * S_LEN * D_CH;
    const unsigned short* Kn = Kb + (size_t)n * S_LEN * D_CH;
    const unsigned short* xn = xb + (size_t)n * C_CH * S_LEN;
    unsigned short* myP = &Plds[wave][0];
    unsigned* myP32 = (unsigned*)myP;

    short8 qf[4];                                    // B[k=d][n=s]: lane n=sl, k=g*8+j (+dc*32)
    #pragma unroll
    for (int dc = 0; dc < 4; ++dc)
        qf[dc] = *reinterpret_cast<const short8*>(Qn + (size_t)(s0 + sl) * D_CH + dc * 32 + g * 8);

    f32x4 oacc[8];                                   // O^T[i][s]: 128 i x 16 s per wave
    #pragma unroll
    for (int i = 0; i < 8; ++i) oacc[i] = (f32x4){0.f, 0.f, 0.f, 0.f};
    float m = -1e30f, lsum = 0.f;

    // ---- stage K tile `it` into LDS slot (64 rows x 256B; wave: 16 rows, 4 insts) ----
    auto kstage = [&](int it, int slot) {
        const int t0 = it * 64;
        #pragma unroll
        for (int i = 0; i < 4; ++i) {
            const int rl = wave * 16 + i * 4 + (lane >> 4);
            const int ch = (lane & 15) ^ (rl & 7);   // LDS[r][q] = G[t0+r][q^(r&7)]
            gload_lds16(Kn + (size_t)(t0 + rl) * D_CH + ch * 8,
                        &Klds[slot][(wave * 16 + i * 4) * 128]);
        }
    };
    // ---- V tile `it` -> registers (wave's i-half: 8 i-tiles x 2 k-steps) ----
    auto vload = [&](int it, short8 (&vb)[16]) {
        const int t0 = it * 64;
        #pragma unroll
        for (int j = 0; j < 8; ++j)
            #pragma unroll
            for (int ks = 0; ks < 2; ++ks)
                vb[j * 2 + ks] = *reinterpret_cast<const short8*>(
                    xn + (size_t)((ih * 8 + j) * 16 + sl) * S_LEN + t0 + ks * 32 + g * 8);
    };

    short8 vA[16], vB[16];
    kstage(0, 0);
    vload(0, vA);
    kstage(1, 1);

    auto body = [&](int it, int slot, short8 (&vuse)[16], short8 (&vnxt)[16]) {
        // Drain K(it); keep K(it+1)[4] + V-prefetch[16] in flight.
        if (it < NT2 - 1) { asm volatile("s_waitcnt vmcnt(20)" ::: "memory"); }
        else              { asm volatile("s_waitcnt vmcnt(16)" ::: "memory"); }
        __builtin_amdgcn_s_barrier();                // all waves: K(it) landed, iter it-1 done
        __builtin_amdgcn_sched_barrier(0);
        if (it + 2 < NT2) {
            const int s2 = slot + 2 >= 3 ? slot - 1 : slot + 2;
            kstage(it + 2, s2);                      // slot last read at it-1: safe
        }
        const unsigned short* Kl = &Klds[slot][0];

        f32x4 sacc[4];
        #pragma unroll
        for (int tt = 0; tt < 4; ++tt) sacc[tt] = (f32x4){0.f, 0.f, 0.f, 0.f};
        __builtin_amdgcn_s_setprio(1);
        #pragma unroll
        for (int dc = 0; dc < 4; ++dc) {             // S^T = K_tile * Q^T (swapped operands)
            const int ch = (dc * 4 + g) ^ (sl & 7);  // un-swizzle
            #pragma unroll
            for (int tt = 0; tt < 4; ++tt) {
                short8 kf = *reinterpret_cast<const short8*>(Kl + (tt * 16 + sl) * 128 + ch * 8);
                sacc[tt] = __builtin_amdgcn_mfma_f32_16x16x32_bf16(kf, qf[dc], sacc[tt], 0, 0, 0);
            }
        }
        __builtin_amdgcn_s_setprio(0);
        // lane holds S[s=sl][t = t0 + tt*16 + g*4 + r]
        float p[16];
        #pragma unroll
        for (int tt = 0; tt < 4; ++tt)
            #pragma unroll
            for (int r = 0; r < 4; ++r) p[tt * 4 + r] = sacc[tt][r];
        float pmax = p[0];
        #pragma unroll
        for (int j = 1; j < 16; ++j) pmax = fmaxf(pmax, p[j]);
        pmax = fmaxf(pmax, __shfl_xor(pmax, 16));
        pmax = fmaxf(pmax, __shfl_xor(pmax, 32));
        const float mnew = fmaxf(m, pmax);
        float rs = 0.f;
        #pragma unroll
        for (int j = 0; j < 16; ++j) {
            p[j] = __builtin_amdgcn_exp2f((p[j] - mnew) * LAMBDA);
            rs += p[j];
        }
        rs += __shfl_xor(rs, 16);
        rs += __shfl_xor(rs, 32);
        if (!__all(mnew == m)) {                     // wave-uniform skip-rescale
            const float alpha = __builtin_amdgcn_exp2f((m - mnew) * LAMBDA);
            lsum *= alpha;
            #pragma unroll
            for (int i = 0; i < 8; ++i) {
                oacc[i][0] *= alpha; oacc[i][1] *= alpha;
                oacc[i][2] *= alpha; oacc[i][3] *= alpha;
            }
            m = mnew;
        }
        lsum += rs;
        // P^T -> LDS via v_cvt_pk_bf16_f32 (T12), then reload as B-fragments.
        #pragma unroll
        for (int tt = 0; tt < 4; ++tt) {
            unsigned pk01, pk23;
            asm("v_cvt_pk_bf16_f32 %0, %1, %2" : "=v"(pk01) : "v"(p[tt * 4 + 0]), "v"(p[tt * 4 + 1]));
            asm("v_cvt_pk_bf16_f32 %0, %1, %2" : "=v"(pk23) : "v"(p[tt * 4 + 2]), "v"(p[tt * 4 + 3]));
            uint2 w; w.x = pk01; w.y = pk23;
            *reinterpret_cast<uint2*>(myP32 + sl * (PITCH / 2) + tt * 8 + g * 2) = w;
        }
        short8 pf0 = *reinterpret_cast<const short8*>(myP + sl * PITCH + g * 8);
        short8 pf1 = *reinterpret_cast<const short8*>(myP + sl * PITCH + 32 + g * 8);
        // O^T += V^T * P^T : wave's i-half, 8 i-tiles x 2 k-steps, V from registers
        __builtin_amdgcn_s_setprio(1);
        #pragma unroll
        for (int j = 0; j < 8; ++j)
            oacc[j] = __builtin_amdgcn_mfma_f32_16x16x32_bf16(vuse[j * 2], pf0, oacc[j], 0, 0, 0);
        #pragma unroll
        for (int j = 0; j < 8; ++j)
            oacc[j] = __builtin_amdgcn_mfma_f32_16x16x32_bf16(vuse[j * 2 + 1], pf1, oacc[j], 0, 0, 0);
        __builtin_amdgcn_s_setprio(0);
        if (it + 1 < NT2) vload(it + 1, vnxt);       // prefetch next V into other reg bank
    };

    #pragma unroll 1
    for (int io = 0; io < NT2 / 2; ++io) {
        const int it = io * 2;
        const int sA = it % 3;
        const int sB = sA + 1 >= 3 ? 0 : sA + 1;
        body(it,     sA, vA, vB);
        body(it + 1, sB, vB, vA);
    }

    const float inv = 1.f / lsum;
    float* on = out + (size_t)n * C_CH * S_LEN;
    #pragma unroll
    for (int j = 0; j < 8; ++j) {
        #pragma unroll
        for (int r = 0; r < 4; ++r) {
            on[(size_t)((ih * 8 + j) * 16 + g * 4 + r) * S_LEN + s0 + sl] = oacc[j][r] * inv;
        }
    }
}

extern "C" void kernel_launch(void* const* d_in, const int* in_sizes, int n_in,
                              void* d_out, int out_size, void* d_ws, size_t ws_size,
                              hipStream_t stream) {
    const float* x  = (const float*)d_in[0];
    const float* tw = (const float*)d_in[1];
    const float* tb = (const float*)d_in[2];
    const float* pw = (const float*)d_in[3];
    const float* pb = (const float*)d_in[4];
    float* out = (float*)d_out;

    char* ws = (char*)d_ws;
    unsigned short* xb = (unsigned short*)(ws);               //  8,388,608 B
    unsigned short* Qb = (unsigned short*)(ws + 8388608);     //  4,194,304 B
    unsigned short* Kb = (unsigned short*)(ws + 12582912);    //  4,194,304 B
    unsigned short* wb = (unsigned short*)(ws + 16777216);    //    131,072 B

    nlm_conv_kernel<<<4096, 256, 0, stream>>>(x, xb);
    nlm_wconv_kernel<<<64, 256, 0, stream>>>(tw, pw, wb);
    nlm_proj_kernel<<<dim3(64, 4), 256, 0, stream>>>(x, wb, tb, pb, Qb, Kb);
    nlm_attn_kernel<<<512, 256, 0, stream>>>(Qb, Kb, xb, out);
}

// Round 5
// 177.622 us; speedup vs baseline: 1.6246x; 1.6246x over previous
//
#include <hip/hip_runtime.h>

#define S_LEN 4096   // H*W
#define C_CH  256
#define D_CH  128
#define NT    128    // t-tiles of 32
// softmax scale folded into exp2: lambda = (1/sqrt(256)) * log2(e)
#define LAMBDA 0.09016844005555896f

typedef __attribute__((ext_vector_type(8))) short short8;   // 8 x bf16 (4 VGPR)
typedef __attribute__((ext_vector_type(4))) float f32x4;

static __device__ __forceinline__ unsigned short f2bf(float x) {
    union { float f; unsigned u; } v; v.f = x;
    unsigned r = v.u + 0x7FFFu + ((v.u >> 16) & 1u);   // RNE
    return (unsigned short)(r >> 16);
}

static __device__ __forceinline__ void gload_lds16(const void* g, void* l) {
    __builtin_amdgcn_global_load_lds(
        (const __attribute__((address_space(1))) void*)g,
        (__attribute__((address_space(3))) void*)l, 16, 0, 0);
}

// ---------- kernel 1: x f32 -> xb bf16, layout [n][c][s] (V operand) ----------
__global__ void nlm_conv_kernel(const float* __restrict__ x, unsigned short* __restrict__ xb) {
    size_t base = ((size_t)blockIdx.x * 256 + threadIdx.x) * 4;
    float4 v = *reinterpret_cast<const float4*>(x + base);
    ushort4 b; b.x = f2bf(v.x); b.y = f2bf(v.y); b.z = f2bf(v.z); b.w = f2bf(v.w);
    *reinterpret_cast<ushort4*>(xb + base) = b;
}

// ---------- kernel 2: theta_w/phi_w f32 -> bf16, wb = [2][128][256] ----------
__global__ void nlm_wconv_kernel(const float* __restrict__ tw, const float* __restrict__ pw,
                                 unsigned short* __restrict__ wb) {
    int base = (blockIdx.x * 256 + threadIdx.x) * 4;
    const float* src = (base < 32768) ? (tw + base) : (pw + base - 32768);
    float4 v = *reinterpret_cast<const float4*>(src);
    ushort4 b; b.x = f2bf(v.x); b.y = f2bf(v.y); b.z = f2bf(v.z); b.w = f2bf(v.w);
    *reinterpret_cast<ushort4*>(wb + base) = b;
}

// ---------- kernel 3: projections Q[n][s][128], K[n][t][128] (bf16) ----------
__launch_bounds__(256, 1)
__global__ void nlm_proj_kernel(const float* __restrict__ x,
                                const unsigned short* __restrict__ wb,
                                const float* __restrict__ tb, const float* __restrict__ pbias,
                                unsigned short* __restrict__ Qb, unsigned short* __restrict__ Kb) {
    const int n    = blockIdx.y;
    const int wave = threadIdx.x >> 6;
    const int lane = threadIdx.x & 63;
    const int sl   = lane & 15, g = lane >> 4;
    const int s0   = blockIdx.x * 64 + wave * 16;
    const float* xn = x + (size_t)n * C_CH * S_LEN;

    f32x4 acc[16];
    #pragma unroll
    for (int i = 0; i < 16; ++i) acc[i] = (f32x4){0.f, 0.f, 0.f, 0.f};

    #pragma unroll 1
    for (int cc = 0; cc < 8; ++cc) {
        short8 af;                                   // A[m=s][k=c]: lane m=sl, k=g*8+j
        #pragma unroll
        for (int j = 0; j < 8; ++j) {
            float v = xn[(size_t)(cc * 32 + g * 8 + j) * S_LEN + s0 + sl];
            af[j] = (short)f2bf(v);
        }
        #pragma unroll
        for (int t = 0; t < 16; ++t) {               // 0..7 theta tiles, 8..15 phi tiles
            const unsigned short* wp = wb + (size_t)(t >> 3) * (D_CH * C_CH)
                                          + (size_t)((t & 7) * 16 + sl) * C_CH + cc * 32 + g * 8;
            short8 bf = *reinterpret_cast<const short8*>(wp);
            acc[t] = __builtin_amdgcn_mfma_f32_16x16x32_bf16(af, bf, acc[t], 0, 0, 0);
        }
    }
    unsigned short* Qn = Qb + (size_t)n * S_LEN * D_CH;
    unsigned short* Kn = Kb + (size_t)n * S_LEN * D_CH;
    #pragma unroll
    for (int t = 0; t < 16; ++t) {
        const float bias = (t < 8 ? tb : pbias)[(t & 7) * 16 + sl];
        unsigned short* dst = (t < 8 ? Qn : Kn);
        #pragma unroll
        for (int r = 0; r < 4; ++r) {                // D row = g*4+r, col = sl
            dst[(size_t)(s0 + g * 4 + r) * D_CH + (t & 7) * 16 + sl] = f2bf(acc[t][r] + bias);
        }
    }
}

// ---------- kernel 4: flash attention, producer/consumer wave split ----------
// 512 blocks (2/CU), 32 q-rows/block. Waves 0/1: QK+softmax (16 rows each) -> P,alpha.
// Waves 2/3: PV (one 16-s-tile, all 256 channels), ONE ITERATION BEHIND via
// double-buffered P/alpha. K: 2-iter-lead LDS pipeline; V: 1-iter lead. Counted vmcnt.
__launch_bounds__(256, 2)
__global__ void nlm_attn_kernel(const unsigned short* __restrict__ Qb,
                                const unsigned short* __restrict__ Kb,
                                const unsigned short* __restrict__ xb,
                                float* __restrict__ out) {
    // XCD swizzle: 512 blocks, 64 consecutive work-items per XCD; 2 XCDs per batch n.
    const int sid   = blockIdx.x;
    const int newb  = (sid & 7) * 64 + (sid >> 3);
    const int n     = newb >> 7;
    const int bx    = newb & 127;
    const int wave  = threadIdx.x >> 6;
    const int lane  = threadIdx.x & 63;
    const int sl    = lane & 15, g = lane >> 4;
    const int sbase = bx * 32;
    const int srow  = (wave & 1) * 16;               // row group (sm) / s-tile base (pv)
    const bool is_sm = (wave < 2);

    __shared__ unsigned short Klds[2][32 * 128];     // [t-local][d], chunk-XOR swizzled
    __shared__ unsigned short Vlds[2][256 * 32];     // [c][t-local], chunk-XOR swizzled
    __shared__ unsigned short Plds[2][32 * 40];      // [s-local][t-local], pitch 40
    __shared__ float alds[2][32];                    // per-row alpha
    __shared__ float linv[32];                       // per-row 1/l

    const unsigned short* Qn = Qb + (size_t)n * S_LEN * D_CH;
    const unsigned short* Kn = Kb + (size_t)n * S_LEN * D_CH;
    const unsigned short* xn = xb + (size_t)n * C_CH * S_LEN;

    // ---- state (role-dependent) ----
    short8 qf[4];
    float m = -1e30f, lsum = 0.f;
    f32x4 oacc[16];                                  // PV: O^T 256 i x 16 s
    if (is_sm) {
        const int s0 = sbase + srow;
        #pragma unroll
        for (int dc = 0; dc < 4; ++dc)
            qf[dc] = *reinterpret_cast<const short8*>(Qn + (size_t)(s0 + sl) * D_CH + dc * 32 + g * 8);
    } else {
        #pragma unroll
        for (int i = 0; i < 16; ++i) oacc[i] = (f32x4){0.f, 0.f, 0.f, 0.f};
    }

    // ---- cooperative staging (all waves) ----
    auto kstage = [&](int it, int buf) {             // 32 rows x 256B, 2 insts/wave
        const int t0 = it * 32;
        #pragma unroll
        for (int i = 0; i < 2; ++i) {
            const int rl = wave * 8 + i * 4 + (lane >> 4);
            const int ch = (lane & 15) ^ (rl & 7);   // LDS[r][q] = G[t0+r][q^(r&7)]
            gload_lds16(Kn + (size_t)(t0 + rl) * D_CH + ch * 8,
                        &Klds[buf][(wave * 8 + i * 4) * 128]);
        }
    };
    auto vstage = [&](int it, int buf) {             // 256 rows x 64B, 4 insts/wave
        const int t0 = it * 32;
        #pragma unroll
        for (int i = 0; i < 4; ++i) {
            const int row = wave * 64 + i * 16 + (lane >> 2);
            const int ch = (lane & 3) ^ ((row >> 1) & 3);
            gload_lds16(xn + (size_t)row * S_LEN + t0 + ch * 8,
                        &Vlds[buf][(wave * 64 + i * 16) * 32]);
        }
    };

    // ---- PV consumer step: O = O*alpha(buf) + V(buf) * P(buf)^T ----
    auto pv_step = [&](int buf) {
        const float a = alds[buf][srow + sl];
        if (!__all(a == 1.0f)) {
            #pragma unroll
            for (int i = 0; i < 16; ++i) {
                oacc[i][0] *= a; oacc[i][1] *= a; oacc[i][2] *= a; oacc[i][3] *= a;
            }
        }
        short8 pf = *reinterpret_cast<const short8*>(&Plds[buf][(srow + sl) * 40 + g * 8]);
        __builtin_amdgcn_s_setprio(1);
        #pragma unroll
        for (int i2 = 0; i2 < 16; ++i2) {
            const int c = i2 * 16 + sl;
            const int ch = g ^ ((sl >> 1) & 3);      // un-swizzle ((c>>1)&3 == (sl>>1)&3)
            short8 vf = *reinterpret_cast<const short8*>(&Vlds[buf][c * 32 + ch * 8]);
            oacc[i2] = __builtin_amdgcn_mfma_f32_16x16x32_bf16(vf, pf, oacc[i2], 0, 0, 0);
        }
        __builtin_amdgcn_s_setprio(0);
    };

    // prologue: K(0), K(1), V(0)  (order matters for vmcnt accounting)
    kstage(0, 0);
    kstage(1, 1);
    vstage(0, 0);

    #pragma unroll 1
    for (int it = 0; it < NT; ++it) {
        const int cur = it & 1;
        // retire K(it) + V(it-1); keep K(it+1)[2] + V(it)[4] in flight
        if (it < NT - 1) { asm volatile("s_waitcnt vmcnt(6)" ::: "memory"); }
        else             { asm volatile("s_waitcnt vmcnt(4)" ::: "memory"); }
        __builtin_amdgcn_s_barrier();
        __builtin_amdgcn_sched_barrier(0);

        if (is_sm) {
            // ---- producer: QK^T + softmax for 16 rows ----
            f32x4 sacc0 = {0.f, 0.f, 0.f, 0.f}, sacc1 = {0.f, 0.f, 0.f, 0.f};
            __builtin_amdgcn_s_setprio(1);
            #pragma unroll
            for (int dc = 0; dc < 4; ++dc) {         // S^T = K_tile * Q^T (swapped)
                const int ch = (dc * 4 + g) ^ (sl & 7);
                short8 kf0 = *reinterpret_cast<const short8*>(&Klds[cur][sl * 128 + ch * 8]);
                short8 kf1 = *reinterpret_cast<const short8*>(&Klds[cur][(16 + sl) * 128 + ch * 8]);
                sacc0 = __builtin_amdgcn_mfma_f32_16x16x32_bf16(kf0, qf[dc], sacc0, 0, 0, 0);
                sacc1 = __builtin_amdgcn_mfma_f32_16x16x32_bf16(kf1, qf[dc], sacc1, 0, 0, 0);
            }
            __builtin_amdgcn_s_setprio(0);
            float p[8];
            p[0] = sacc0[0]; p[1] = sacc0[1]; p[2] = sacc0[2]; p[3] = sacc0[3];
            p[4] = sacc1[0]; p[5] = sacc1[1]; p[6] = sacc1[2]; p[7] = sacc1[3];
            float pmax = fmaxf(fmaxf(fmaxf(p[0], p[1]), fmaxf(p[2], p[3])),
                               fmaxf(fmaxf(p[4], p[5]), fmaxf(p[6], p[7])));
            pmax = fmaxf(pmax, __shfl_xor(pmax, 16));
            pmax = fmaxf(pmax, __shfl_xor(pmax, 32));
            const float mnew = fmaxf(m, pmax);
            float rs = 0.f;
            #pragma unroll
            for (int j = 0; j < 8; ++j) {
                p[j] = __builtin_amdgcn_exp2f((p[j] - mnew) * LAMBDA);
                rs += p[j];
            }
            rs += __shfl_xor(rs, 16);
            rs += __shfl_xor(rs, 32);
            float alpha = 1.0f;
            if (!__all(mnew == m)) {                 // wave-uniform skip-rescale
                alpha = __builtin_amdgcn_exp2f((m - mnew) * LAMBDA);
                lsum *= alpha;
                m = mnew;
            }
            lsum += rs;
            alds[cur][srow + sl] = alpha;            // all g write same value (benign)
            // P -> LDS via v_cvt_pk_bf16_f32: row srow+sl, elems {g*4..}, {16+g*4..}
            unsigned pk01, pk23, pk45, pk67;
            asm("v_cvt_pk_bf16_f32 %0, %1, %2" : "=v"(pk01) : "v"(p[0]), "v"(p[1]));
            asm("v_cvt_pk_bf16_f32 %0, %1, %2" : "=v"(pk23) : "v"(p[2]), "v"(p[3]));
            asm("v_cvt_pk_bf16_f32 %0, %1, %2" : "=v"(pk45) : "v"(p[4]), "v"(p[5]));
            asm("v_cvt_pk_bf16_f32 %0, %1, %2" : "=v"(pk67) : "v"(p[6]), "v"(p[7]));
            unsigned* pr = (unsigned*)&Plds[cur][(srow + sl) * 40];
            uint2 wlo; wlo.x = pk01; wlo.y = pk23;
            uint2 whi; whi.x = pk45; whi.y = pk67;
            *reinterpret_cast<uint2*>(pr + g * 2)     = wlo;   // t = g*4+r
            *reinterpret_cast<uint2*>(pr + 8 + g * 2) = whi;   // t = 16+g*4+r
        } else if (it > 0) {
            // ---- consumer: PV for tile it-1 ----
            pv_step(cur ^ 1);
        }

        asm volatile("s_waitcnt lgkmcnt(0)" ::: "memory");
        __builtin_amdgcn_sched_barrier(0);
        __builtin_amdgcn_s_barrier();                // staging may now overwrite
        if (it + 2 < NT) kstage(it + 2, cur);        // Klds[cur] freed this iter
        if (it + 1 < NT) vstage(it + 1, cur ^ 1);    // Vlds[cur^1] (V(it-1)) freed
    }

    // ---- epilogue: drain PV for tile NT-1, normalize, store ----
    asm volatile("s_waitcnt vmcnt(0)" ::: "memory");
    if (is_sm) linv[srow + sl] = 1.0f / lsum;
    asm volatile("s_waitcnt lgkmcnt(0)" ::: "memory");
    __builtin_amdgcn_sched_barrier(0);
    __builtin_amdgcn_s_barrier();
    if (!is_sm) {
        pv_step((NT - 1) & 1);
        const float li = linv[srow + sl];
        float* on = out + (size_t)n * C_CH * S_LEN;
        #pragma unroll
        for (int i2 = 0; i2 < 16; ++i2) {
            #pragma unroll
            for (int r = 0; r < 4; ++r) {
                on[(size_t)(i2 * 16 + g * 4 + r) * S_LEN + sbase + srow + sl] = oacc[i2][r] * li;
            }
        }
    }
}

extern "C" void kernel_launch(void* const* d_in, const int* in_sizes, int n_in,
                              void* d_out, int out_size, void* d_ws, size_t ws_size,
                              hipStream_t stream) {
    const float* x  = (const float*)d_in[0];
    const float* tw = (const float*)d_in[1];
    const float* tb = (const float*)d_in[2];
    const float* pw = (const float*)d_in[3];
    const float* pb = (const float*)d_in[4];
    float* out = (float*)d_out;

    char* ws = (char*)d_ws;
    unsigned short* xb = (unsigned short*)(ws);               //  8,388,608 B
    unsigned short* Qb = (unsigned short*)(ws + 8388608);     //  4,194,304 B
    unsigned short* Kb = (unsigned short*)(ws + 12582912);    //  4,194,304 B
    unsigned short* wb = (unsigned short*)(ws + 16777216);    //    131,072 B

    nlm_conv_kernel<<<4096, 256, 0, stream>>>(x, xb);
    nlm_wconv_kernel<<<64, 256, 0, stream>>>(tw, pw, wb);
    nlm_proj_kernel<<<dim3(64, 4), 256, 0, stream>>>(x, wb, tb, pb, Qb, Kb);
    nlm_attn_kernel<<<512, 256, 0, stream>>>(Qb, Kb, xb, out);
}